// Round 15
// baseline (365.195 us; speedup 1.0000x reference)
//
#include <hip/hip_runtime.h>
#include <hip/hip_bf16.h>

#define NN 100000
#define NE 1200000
#define IND 128
#define HID 64
#define NC 5
#define NG 128
#define NB 391    // ceil(NN/256)
#define GB 1172   // bucket blocks (GB*256*4 >= NE)
#define G1 3125   // gemm1 blocks (NN/32)

typedef float v2f __attribute__((ext_vector_type(2)));
typedef unsigned int v4u __attribute__((ext_vector_type(4)));

static __device__ __forceinline__ float bf2f(unsigned short u) {
    union { unsigned int i; float f; } x;
    x.i = (unsigned int)u << 16;
    return x.f;
}
static __device__ __forceinline__ unsigned short f2bf(float f) {
    union { float f; unsigned int i; } x;
    x.f = f;
    unsigned int r = (x.i + 0x7fffu + ((x.i >> 16) & 1u)) >> 16;  // RNE
    return (unsigned short)r;
}
// pack 2 f32 -> 2 fp8 (hardware, e4m3 on gfx950)
static __device__ __forceinline__ unsigned short f2fp8x2(float a, float b) {
    int p = __builtin_amdgcn_cvt_pk_fp8_f32(a, b, 0, false);
    return (unsigned short)(p & 0xffff);
}
// decode 4 fp8 (one uint) and accumulate into a0..a3
static __device__ __forceinline__ void fp8acc(unsigned int u, float& a0, float& a1, float& a2, float& a3) {
    v2f lo = __builtin_amdgcn_cvt_pk_f32_fp8(u, false);
    v2f hi = __builtin_amdgcn_cvt_pk_f32_fp8(u, true);
    a0 += lo.x; a1 += lo.y; a2 += hi.x; a3 += hi.y;
}

// ---------------- CSR build ----------------
__global__ __launch_bounds__(256) void k_hist(const int* __restrict__ dst, int* __restrict__ cnt,
                                              int* __restrict__ rank) {
    int e = blockIdx.x * 256 + threadIdx.x;
    if (e < NE) {
        int d = __builtin_nontemporal_load(&dst[e]);
        int r = atomicAdd(&cnt[d], 1);
        __builtin_nontemporal_store(r, &rank[e]);
    }
}

__global__ __launch_bounds__(256) void k_scan1(const int* __restrict__ cnt, int* __restrict__ exc,
                                               int* __restrict__ bsum, float* __restrict__ dinv) {
    __shared__ int lds[256];
    int tid = threadIdx.x;
    int i = blockIdx.x * 256 + tid;
    int v = (i < NN) ? cnt[i] : 0;
    lds[tid] = v;
    __syncthreads();
    for (int off = 1; off < 256; off <<= 1) {
        int t = (tid >= off) ? lds[tid - off] : 0;
        __syncthreads();
        lds[tid] += t;
        __syncthreads();
    }
    if (i < NN) {
        exc[i] = lds[tid] - v;
        dinv[i] = rsqrtf((float)v + 1.0f);
    }
    if (tid == 255) bsum[blockIdx.x] = lds[255];
}

__global__ __launch_bounds__(256) void k_scan23(const int* __restrict__ exc, const int* __restrict__ bsum,
                                                int* __restrict__ row_ptr) {
    __shared__ int lds[256];
    int tid = threadIdx.x;
    int me = blockIdx.x;
    int v = 0;
    if (tid < me) v = bsum[tid];
    if (tid + 256 < me) v += bsum[tid + 256];
    lds[tid] = v;
    __syncthreads();
    for (int off = 128; off > 0; off >>= 1) {
        if (tid < off) lds[tid] += lds[tid + off];
        __syncthreads();
    }
    int base = lds[0];
    int i = me * 256 + tid;
    if (i < NN) row_ptr[i] = exc[i] + base;
    if (i == 0) row_ptr[NN] = NE;
}

// ---------------- fused grid: bucket | layer-1 GEMM (fp8 out) | bounds ----------------
__global__ __launch_bounds__(256) void k_fused1(
    const float* __restrict__ X, const float* __restrict__ W,
    const float* __restrict__ dinv, unsigned short* __restrict__ out_f8,
    const int* __restrict__ src, const int* __restrict__ dst,
    const int* __restrict__ row_ptr, const int* __restrict__ rank,
    int* __restrict__ src_sorted,
    const int* __restrict__ batch, int* __restrict__ start)
{
    __shared__ float lds[IND * HID + 32 * IND];  // 48 KB (gemm1 segment only)
    int tid = threadIdx.x;

    if (blockIdx.x < GB) {
        int t = blockIdx.x * 256 + tid;
        const int T = GB * 256;
#pragma unroll
        for (int u = 0; u < 4; ++u) {
            int e = t + u * T;
            if (e < NE) {
                int d = __builtin_nontemporal_load(&dst[e]);
                int s = __builtin_nontemporal_load(&src[e]);
                int r = __builtin_nontemporal_load(&rank[e]);
                src_sorted[row_ptr[d] + r] = s;   // keep cached: L2 coalesces partial lines
            }
        }
        return;
    }
    if (blockIdx.x >= GB + G1) {
        int i = (blockIdx.x - GB - G1) * 256 + tid;
        if (i >= NN) return;
        int b = batch[i];
        if (i == 0) {
            for (int g = 0; g <= b; ++g) start[g] = 0;
        } else {
            int p = batch[i - 1];
            for (int g = p + 1; g <= b; ++g) start[g] = i;
        }
        if (i == NN - 1) {
            for (int g = b + 1; g <= NG; ++g) start[g] = NN;
        }
        return;
    }

    // ---- gemm1: thread owns adjacent cols {2c, 2c+1} for fp8 pair-packing ----
    float* Wl = lds;             // [128][64]
    float* xl = lds + IND * HID; // [32][128]
    int n0 = (blockIdx.x - GB) * 32;
    int c = tid & 31;
    int s = tid >> 5;

    {
        const float4* Wg = (const float4*)W;
        float4* Wl4 = (float4*)Wl;
#pragma unroll
        for (int i = 0; i < IND * 16 / 256; ++i) Wl4[i * 256 + tid] = Wg[i * 256 + tid];
    }
    {
        const float4* Xg = (const float4*)X;
        float4* xl4 = (float4*)xl;
        const float4 z = {0.f, 0.f, 0.f, 0.f};
#pragma unroll
        for (int i = 0; i < 32 * IND / 4 / 256; ++i) {
            int idx = i * 256 + tid;
            int node = n0 + idx / (IND / 4);
            xl4[idx] = (node < NN) ? Xg[(size_t)n0 * (IND / 4) + idx] : z;
        }
    }
    __syncthreads();

    float acc[4][2];
#pragma unroll
    for (int r = 0; r < 4; ++r) { acc[r][0] = 0.f; acc[r][1] = 0.f; }

#pragma unroll 4
    for (int k0 = 0; k0 < IND; k0 += 4) {
        float4 xv[4];
#pragma unroll
        for (int r = 0; r < 4; ++r) xv[r] = *(const float4*)&xl[(s * 4 + r) * IND + k0];
#pragma unroll
        for (int kk = 0; kk < 4; ++kk) {
            float w0 = Wl[(k0 + kk) * HID + 2 * c];
            float w1 = Wl[(k0 + kk) * HID + 2 * c + 1];
#pragma unroll
            for (int r = 0; r < 4; ++r) {
                float xe = (kk == 0) ? xv[r].x : (kk == 1) ? xv[r].y : (kk == 2) ? xv[r].z : xv[r].w;
                acc[r][0] = fmaf(xe, w0, acc[r][0]);
                acc[r][1] = fmaf(xe, w1, acc[r][1]);
            }
        }
    }

#pragma unroll
    for (int r = 0; r < 4; ++r) {
        int n = n0 + s * 4 + r;
        if (n < NN) {
            float dn = dinv[n];
            out_f8[(size_t)n * 32 + c] = f2fp8x2(acc[r][0] * dn, acc[r][1] * dn);
        }
    }
}

// ---------------- aggregate: 8 nodes/wave, 2 batches x 4 streams; NT on streams ----------------
__global__ __launch_bounds__(256) void k_aggregate(const unsigned int* __restrict__ hW8,  // fp8 rows: 16 uints
                                                   const int* __restrict__ srcs,
                                                   const int* __restrict__ row_ptr,
                                                   const float* __restrict__ dinv,
                                                   const float* __restrict__ bias,
                                                   unsigned int* __restrict__ outb) {    // bf16 rows: 32 uints
    int tid = threadIdx.x;
    int lane = tid & 63;
    int grp = lane >> 4;   // 0..3
    int li = lane & 15;
    int w = tid >> 6;
    int base = (blockIdx.x * 4 + w) * 8;   // NN = 12500*8, always valid

    // coalesced bounds load: lane i<=8 holds row_ptr[base+i]
    int rp = row_ptr[base + (lane <= 8 ? lane : 8)];
    float4 bv = ((const float4*)bias)[li];

#pragma unroll
    for (int q = 0; q < 2; ++q) {
        int n0 = base + 4 * q;
        int e0 = __shfl(rp, 4 * q + 0, 64);
        int f0 = __shfl(rp, 4 * q + 1, 64);
        int e1 = f0;
        int f1 = __shfl(rp, 4 * q + 2, 64);
        int e2 = f1;
        int f2 = __shfl(rp, 4 * q + 3, 64);
        int e3 = f2;
        int f3 = __shfl(rp, 4 * q + 4, 64);

        float A0 = 0.f, A1 = 0.f, A2 = 0.f, A3 = 0.f;
        float B0 = 0.f, B1 = 0.f, B2 = 0.f, B3 = 0.f;
        float C0 = 0.f, C1 = 0.f, C2 = 0.f, C3 = 0.f;
        float D0 = 0.f, D1 = 0.f, D2 = 0.f, D3 = 0.f;

        // self terms: one 256B coalesced gather covers all 4 nodes (grp g -> node n0+g)
        {
            unsigned int su = hW8[(size_t)(n0 + grp) * 16 + li];
            if (grp == 0)      fp8acc(su, A0, A1, A2, A3);
            else if (grp == 1) fp8acc(su, B0, B1, B2, B3);
            else if (grp == 2) fp8acc(su, C0, C1, C2, C3);
            else               fp8acc(su, D0, D1, D2, D3);
        }

        // quad main loop: 4 independent gathers in flight
        while (e0 + 3 < f0 && e1 + 3 < f1 && e2 + 3 < f2 && e3 + 3 < f3) {
            int s0 = __builtin_nontemporal_load(&srcs[e0 + grp]);
            int s1 = __builtin_nontemporal_load(&srcs[e1 + grp]);
            int s2 = __builtin_nontemporal_load(&srcs[e2 + grp]);
            int s3 = __builtin_nontemporal_load(&srcs[e3 + grp]);
            unsigned int u0 = hW8[(size_t)s0 * 16 + li];
            unsigned int u1 = hW8[(size_t)s1 * 16 + li];
            unsigned int u2 = hW8[(size_t)s2 * 16 + li];
            unsigned int u3 = hW8[(size_t)s3 * 16 + li];
            fp8acc(u0, A0, A1, A2, A3);
            fp8acc(u1, B0, B1, B2, B3);
            fp8acc(u2, C0, C1, C2, C3);
            fp8acc(u3, D0, D1, D2, D3);
            e0 += 4; e1 += 4; e2 += 4; e3 += 4;
        }
        // per-stream drains (wave-uniform bounds)
        while (e0 + 3 < f0) {
            int s0 = __builtin_nontemporal_load(&srcs[e0 + grp]);
            unsigned int u0 = hW8[(size_t)s0 * 16 + li];
            fp8acc(u0, A0, A1, A2, A3);
            e0 += 4;
        }
        while (e1 + 3 < f1) {
            int s1 = __builtin_nontemporal_load(&srcs[e1 + grp]);
            unsigned int u1 = hW8[(size_t)s1 * 16 + li];
            fp8acc(u1, B0, B1, B2, B3);
            e1 += 4;
        }
        while (e2 + 3 < f2) {
            int s2 = __builtin_nontemporal_load(&srcs[e2 + grp]);
            unsigned int u2 = hW8[(size_t)s2 * 16 + li];
            fp8acc(u2, C0, C1, C2, C3);
            e2 += 4;
        }
        while (e3 + 3 < f3) {
            int s3 = __builtin_nontemporal_load(&srcs[e3 + grp]);
            unsigned int u3 = hW8[(size_t)s3 * 16 + li];
            fp8acc(u3, D0, D1, D2, D3);
            e3 += 4;
        }
        // tails (0..3 edges each), predicated by group
        if (grp < f0 - e0) {
            int s0 = __builtin_nontemporal_load(&srcs[e0 + grp]);
            unsigned int u0 = hW8[(size_t)s0 * 16 + li];
            fp8acc(u0, A0, A1, A2, A3);
        }
        if (grp < f1 - e1) {
            int s1 = __builtin_nontemporal_load(&srcs[e1 + grp]);
            unsigned int u1 = hW8[(size_t)s1 * 16 + li];
            fp8acc(u1, B0, B1, B2, B3);
        }
        if (grp < f2 - e2) {
            int s2 = __builtin_nontemporal_load(&srcs[e2 + grp]);
            unsigned int u2 = hW8[(size_t)s2 * 16 + li];
            fp8acc(u2, C0, C1, C2, C3);
        }
        if (grp < f3 - e3) {
            int s3 = __builtin_nontemporal_load(&srcs[e3 + grp]);
            unsigned int u3 = hW8[(size_t)s3 * 16 + li];
            fp8acc(u3, D0, D1, D2, D3);
        }

        // cross-group reduce, all 4 streams
#define RED1(x) x += __shfl_xor(x, 16, 64)
#define RED2(x) x += __shfl_xor(x, 32, 64)
        RED1(A0); RED1(A1); RED1(A2); RED1(A3);
        RED1(B0); RED1(B1); RED1(B2); RED1(B3);
        RED1(C0); RED1(C1); RED1(C2); RED1(C3);
        RED1(D0); RED1(D1); RED1(D2); RED1(D3);
        RED2(A0); RED2(A1); RED2(A2); RED2(A3);
        RED2(B0); RED2(B1); RED2(B2); RED2(B3);
        RED2(C0); RED2(C1); RED2(C2); RED2(C3);
        RED2(D0); RED2(D1); RED2(D2); RED2(D3);
#undef RED1
#undef RED2

        // store: grp g stores node n0+g -> one fully coalesced NT store (bypass L2)
        {
            int n = n0 + grp;
            float s0v, s1v, s2v, s3v;
            if (grp == 0)      { s0v = A0; s1v = A1; s2v = A2; s3v = A3; }
            else if (grp == 1) { s0v = B0; s1v = B1; s2v = B2; s3v = B3; }
            else if (grp == 2) { s0v = C0; s1v = C1; s2v = C2; s3v = C3; }
            else               { s0v = D0; s1v = D1; s2v = D2; s3v = D3; }
            float dn = dinv[n];
            float v0 = fmaxf(fmaf(dn, s0v, bv.x), 0.0f);
            float v1 = fmaxf(fmaf(dn, s1v, bv.y), 0.0f);
            float v2 = fmaxf(fmaf(dn, s2v, bv.z), 0.0f);
            float v3 = fmaxf(fmaf(dn, s3v, bv.w), 0.0f);
            unsigned long long pk =
                (unsigned long long)((unsigned int)f2bf(v0) | ((unsigned int)f2bf(v1) << 16)) |
                ((unsigned long long)((unsigned int)f2bf(v2) | ((unsigned int)f2bf(v3) << 16)) << 32);
            __builtin_nontemporal_store(pk, (unsigned long long*)outb + (size_t)n * 16 + li);
        }
    }
}

// ---------------- GEMM layers 2/3: bf16 in (NT), fp8 out (cached) ----------------
__global__ __launch_bounds__(256) void k_gemm_bf(const unsigned short* __restrict__ X,
                                                 const float* __restrict__ W,
                                                 const float* __restrict__ dinv,
                                                 unsigned short* __restrict__ out_f8) {
    __shared__ float Wl[HID * HID];  // 16 KB
    __shared__ float xl[64 * HID];   // 16 KB
    int tid = threadIdx.x;
    int n0 = blockIdx.x * 64;

    {
        const float4* Wg = (const float4*)W;
        float4* Wl4 = (float4*)Wl;
#pragma unroll
        for (int i = 0; i < HID * HID / 4 / 256; ++i) Wl4[i * 256 + tid] = Wg[i * 256 + tid];
    }
    {
        const v4u* Xg = (const v4u*)X;
#pragma unroll
        for (int i = 0; i < 2; ++i) {
            int idx = i * 256 + tid;      // 0..511
            int ln = idx >> 3;            // local node
            int k0 = (idx & 7) * 8;
            int node = n0 + ln;
            float f[8];
            if (node < NN) {
                v4u u = __builtin_nontemporal_load(&Xg[(size_t)n0 * 8 + idx]);
                f[0] = bf2f((unsigned short)(u.x & 0xffff));
                f[1] = bf2f((unsigned short)(u.x >> 16));
                f[2] = bf2f((unsigned short)(u.y & 0xffff));
                f[3] = bf2f((unsigned short)(u.y >> 16));
                f[4] = bf2f((unsigned short)(u.z & 0xffff));
                f[5] = bf2f((unsigned short)(u.z >> 16));
                f[6] = bf2f((unsigned short)(u.w & 0xffff));
                f[7] = bf2f((unsigned short)(u.w >> 16));
            } else {
#pragma unroll
                for (int q = 0; q < 8; ++q) f[q] = 0.f;
            }
#pragma unroll
            for (int q = 0; q < 8; ++q) xl[ln * HID + k0 + q] = f[q];
        }
    }
    __syncthreads();

    int c = tid & 31;
    int s = tid >> 5;
    float acc[8][2];
#pragma unroll
    for (int r = 0; r < 8; ++r) { acc[r][0] = 0.f; acc[r][1] = 0.f; }

#pragma unroll 4
    for (int k0 = 0; k0 < HID; k0 += 4) {
        float4 xv[8];
#pragma unroll
        for (int r = 0; r < 8; ++r) xv[r] = *(const float4*)&xl[(s * 8 + r) * HID + k0];
#pragma unroll
        for (int kk = 0; kk < 4; ++kk) {
            float w0 = Wl[(k0 + kk) * HID + 2 * c];
            float w1 = Wl[(k0 + kk) * HID + 2 * c + 1];
#pragma unroll
            for (int r = 0; r < 8; ++r) {
                float xe = (kk == 0) ? xv[r].x : (kk == 1) ? xv[r].y : (kk == 2) ? xv[r].z : xv[r].w;
                acc[r][0] = fmaf(xe, w0, acc[r][0]);
                acc[r][1] = fmaf(xe, w1, acc[r][1]);
            }
        }
    }

#pragma unroll
    for (int r = 0; r < 8; ++r) {
        int n = n0 + s * 8 + r;
        if (n < NN) {
            float dn = dinv[n];
            out_f8[(size_t)n * 32 + c] = f2fp8x2(acc[r][0] * dn, acc[r][1] * dn);
        }
    }
}

// ---------------- pooling stage A: parallel partial sums over 128-node chunks ----------------
__global__ __launch_bounds__(256) void k_pool_partial(const unsigned short* __restrict__ h,
                                                      const int* __restrict__ batch,
                                                      float* __restrict__ sums) {
    int tid = threadIdx.x;
    int j = tid & 63;
    int w = tid >> 6;
    int chunk = blockIdx.x * 4 + w;
    int n0 = chunk * 128;
    if (n0 >= NN) return;
    int n1 = n0 + 128;
    if (n1 > NN) n1 = NN;
    float acc = 0.0f;
    int cur = batch[n0];
    for (int n = n0; n < n1; ++n) {
        int g = batch[n];
        if (g != cur) {
            atomicAdd(&sums[cur * HID + j], acc);
            acc = 0.0f;
            cur = g;
        }
        acc += bf2f(h[n * HID + j]);
    }
    atomicAdd(&sums[cur * HID + j], acc);
}

// ---------------- pooling stage B: mean + head ----------------
__global__ __launch_bounds__(64) void k_head(const float* __restrict__ sums, const int* __restrict__ start,
                                             const float* __restrict__ Wc, const float* __restrict__ bc,
                                             float* __restrict__ out) {
    int g = blockIdx.x;
    int j = threadIdx.x;
    float cnt = (float)(start[g + 1] - start[g]);
    float p = sums[g * HID + j] / fmaxf(cnt, 1.0f);
#pragma unroll
    for (int c = 0; c < NC; ++c) {
        float v = p * Wc[j * NC + c];
        for (int off = 32; off > 0; off >>= 1) v += __shfl_down(v, off);
        if (j == 0) out[g * NC + c] = v + bc[c];
    }
}

// ---------------- driver ----------------
extern "C" void kernel_launch(void* const* d_in, const int* in_sizes, int n_in,
                              void* d_out, int out_size, void* d_ws, size_t ws_size,
                              hipStream_t stream) {
    const float* x  = (const float*)d_in[0];
    const int* ei   = (const int*)d_in[1];
    const int* bat  = (const int*)d_in[2];
    const float* W1 = (const float*)d_in[3];
    const float* b1 = (const float*)d_in[4];
    const float* W2 = (const float*)d_in[5];
    const float* b2 = (const float*)d_in[6];
    const float* W3 = (const float*)d_in[7];
    const float* b3 = (const float*)d_in[8];
    const float* Wc = (const float*)d_in[9];
    const float* bc = (const float*)d_in[10];
    float* out = (float*)d_out;

    const int* src = ei;
    const int* dst = ei + NE;

    // workspace layout (bytes), all 16B-aligned
    char* wsb = (char*)d_ws;
    float* dinv         = (float*)wsb;                          // NN f32
    int*   row_ptr      = (int*)(wsb + 400000);                 // NN+1
    int*   srcs         = (int*)(wsb + 800016);                 // NE
    unsigned short* hF8 = (unsigned short*)(wsb + 5600016);     // NN*HID fp8 (6.4 MB)
    unsigned short* hBF = (unsigned short*)(wsb + 18400016);    // NN*HID bf16 (12.8 MB)
    int*   cnt          = (int*)(wsb + 31200016);               // NN
    int*   exc          = (int*)(wsb + 31600016);               // NN
    int*   bsum         = (int*)(wsb + 32000016);               // 512
    int*   rank         = (int*)(wsb + 32002064);               // NE
    int*   start        = (int*)(wsb + 36802064);               // NG+1
    float* sums         = (float*)(wsb + 36803088);             // NG*HID f32 (32 KB)

    const int gE = (NE + 255) / 256;  // 4688

    // CSR build + normalization
    hipMemsetAsync(cnt, 0, NN * sizeof(int), stream);
    hipMemsetAsync(sums, 0, NG * HID * sizeof(float), stream);
    k_hist<<<gE, 256, 0, stream>>>(dst, cnt, rank);
    k_scan1<<<NB, 256, 0, stream>>>(cnt, exc, bsum, dinv);
    k_scan23<<<NB, 256, 0, stream>>>(exc, bsum, row_ptr);

    // bucket scatter + layer-1 GEMM (fp8 out) + pool bounds, one grid
    k_fused1<<<GB + G1 + NB, 256, 0, stream>>>(x, W1, dinv, hF8, src, dst, row_ptr, rank, srcs, bat, start);

    // layers: gemm writes fp8 (gathered, cached), aggregate writes bf16 (streamed, NT)
    k_aggregate<<<NN / 32, 256, 0, stream>>>((const unsigned int*)hF8, srcs, row_ptr, dinv, b1, (unsigned int*)hBF);
    k_gemm_bf<<<(NN + 63) / 64, 256, 0, stream>>>(hBF, W2, dinv, hF8);
    k_aggregate<<<NN / 32, 256, 0, stream>>>((const unsigned int*)hF8, srcs, row_ptr, dinv, b2, (unsigned int*)hBF);
    k_gemm_bf<<<(NN + 63) / 64, 256, 0, stream>>>(hBF, W3, dinv, hF8);
    k_aggregate<<<NN / 32, 256, 0, stream>>>((const unsigned int*)hF8, srcs, row_ptr, dinv, b3, (unsigned int*)hBF);

    // pooling: parallel partials + tiny head
    k_pool_partial<<<196, 256, 0, stream>>>(hBF, bat, sums);
    k_head<<<NG, 64, 0, stream>>>(sums, start, Wc, bc, out);
}

// Round 16
// 310.410 us; speedup vs baseline: 1.1765x; 1.1765x over previous
//
#include <hip/hip_runtime.h>
#include <hip/hip_bf16.h>

#define NN 100000
#define NE 1200000
#define IND 128
#define HID 64
#define NC 5
#define NG 128
#define NB 391    // ceil(NN/256)
#define GB 1172   // bucket blocks (GB*256*4 >= NE)
#define G1 3125   // gemm1 blocks (NN/32)

typedef float v2f __attribute__((ext_vector_type(2)));

static __device__ __forceinline__ float bf2f(unsigned short u) {
    union { unsigned int i; float f; } x;
    x.i = (unsigned int)u << 16;
    return x.f;
}
static __device__ __forceinline__ unsigned short f2bf(float f) {
    union { float f; unsigned int i; } x;
    x.f = f;
    unsigned int r = (x.i + 0x7fffu + ((x.i >> 16) & 1u)) >> 16;  // RNE
    return (unsigned short)r;
}
// pack 2 f32 -> 2 fp8 (hardware, e4m3 on gfx950)
static __device__ __forceinline__ unsigned short f2fp8x2(float a, float b) {
    int p = __builtin_amdgcn_cvt_pk_fp8_f32(a, b, 0, false);
    return (unsigned short)(p & 0xffff);
}
// decode 4 fp8 (one uint) and accumulate into a0..a3
static __device__ __forceinline__ void fp8acc(unsigned int u, float& a0, float& a1, float& a2, float& a3) {
    v2f lo = __builtin_amdgcn_cvt_pk_f32_fp8(u, false);
    v2f hi = __builtin_amdgcn_cvt_pk_f32_fp8(u, true);
    a0 += lo.x; a1 += lo.y; a2 += hi.x; a3 += hi.y;
}

// ---------------- CSR build ----------------
__global__ __launch_bounds__(256) void k_hist(const int* __restrict__ dst, int* __restrict__ cnt,
                                              int* __restrict__ rank) {
    int e = blockIdx.x * 256 + threadIdx.x;
    if (e < NE) rank[e] = atomicAdd(&cnt[dst[e]], 1);
}

__global__ __launch_bounds__(256) void k_scan1(const int* __restrict__ cnt, int* __restrict__ exc,
                                               int* __restrict__ bsum, float* __restrict__ dinv) {
    __shared__ int lds[256];
    int tid = threadIdx.x;
    int i = blockIdx.x * 256 + tid;
    int v = (i < NN) ? cnt[i] : 0;
    lds[tid] = v;
    __syncthreads();
    for (int off = 1; off < 256; off <<= 1) {
        int t = (tid >= off) ? lds[tid - off] : 0;
        __syncthreads();
        lds[tid] += t;
        __syncthreads();
    }
    if (i < NN) {
        exc[i] = lds[tid] - v;
        dinv[i] = rsqrtf((float)v + 1.0f);
    }
    if (tid == 255) bsum[blockIdx.x] = lds[255];
}

__global__ __launch_bounds__(256) void k_scan23(const int* __restrict__ exc, const int* __restrict__ bsum,
                                                int* __restrict__ row_ptr) {
    __shared__ int lds[256];
    int tid = threadIdx.x;
    int me = blockIdx.x;
    int v = 0;
    if (tid < me) v = bsum[tid];
    if (tid + 256 < me) v += bsum[tid + 256];
    lds[tid] = v;
    __syncthreads();
    for (int off = 128; off > 0; off >>= 1) {
        if (tid < off) lds[tid] += lds[tid + off];
        __syncthreads();
    }
    int base = lds[0];
    int i = me * 256 + tid;
    if (i < NN) row_ptr[i] = exc[i] + base;
    if (i == 0) row_ptr[NN] = NE;
}

// ---------------- fused grid: bucket | layer-1 GEMM (fp8 out) | bounds ----------------
__global__ __launch_bounds__(256) void k_fused1(
    const float* __restrict__ X, const float* __restrict__ W,
    const float* __restrict__ dinv, unsigned short* __restrict__ out_f8,
    const int* __restrict__ src, const int* __restrict__ dst,
    const int* __restrict__ row_ptr, const int* __restrict__ rank,
    int* __restrict__ src_sorted,
    const int* __restrict__ batch, int* __restrict__ start)
{
    __shared__ float lds[IND * HID + 32 * IND];  // 48 KB (gemm1 segment only)
    int tid = threadIdx.x;

    if (blockIdx.x < GB) {
        int t = blockIdx.x * 256 + tid;
        const int T = GB * 256;
#pragma unroll
        for (int u = 0; u < 4; ++u) {
            int e = t + u * T;
            if (e < NE) src_sorted[row_ptr[dst[e]] + rank[e]] = src[e];
        }
        return;
    }
    if (blockIdx.x >= GB + G1) {
        int i = (blockIdx.x - GB - G1) * 256 + tid;
        if (i >= NN) return;
        int b = batch[i];
        if (i == 0) {
            for (int g = 0; g <= b; ++g) start[g] = 0;
        } else {
            int p = batch[i - 1];
            for (int g = p + 1; g <= b; ++g) start[g] = i;
        }
        if (i == NN - 1) {
            for (int g = b + 1; g <= NG; ++g) start[g] = NN;
        }
        return;
    }

    // ---- gemm1: thread owns adjacent cols {2c, 2c+1} for fp8 pair-packing ----
    float* Wl = lds;             // [128][64]
    float* xl = lds + IND * HID; // [32][128]
    int n0 = (blockIdx.x - GB) * 32;
    int c = tid & 31;
    int s = tid >> 5;

    {
        const float4* Wg = (const float4*)W;
        float4* Wl4 = (float4*)Wl;
#pragma unroll
        for (int i = 0; i < IND * 16 / 256; ++i) Wl4[i * 256 + tid] = Wg[i * 256 + tid];
    }
    {
        const float4* Xg = (const float4*)X;
        float4* xl4 = (float4*)xl;
        const float4 z = {0.f, 0.f, 0.f, 0.f};
#pragma unroll
        for (int i = 0; i < 32 * IND / 4 / 256; ++i) {
            int idx = i * 256 + tid;
            int node = n0 + idx / (IND / 4);
            xl4[idx] = (node < NN) ? Xg[(size_t)n0 * (IND / 4) + idx] : z;
        }
    }
    __syncthreads();

    float acc[4][2];
#pragma unroll
    for (int r = 0; r < 4; ++r) { acc[r][0] = 0.f; acc[r][1] = 0.f; }

#pragma unroll 4
    for (int k0 = 0; k0 < IND; k0 += 4) {
        float4 xv[4];
#pragma unroll
        for (int r = 0; r < 4; ++r) xv[r] = *(const float4*)&xl[(s * 4 + r) * IND + k0];
#pragma unroll
        for (int kk = 0; kk < 4; ++kk) {
            float w0 = Wl[(k0 + kk) * HID + 2 * c];
            float w1 = Wl[(k0 + kk) * HID + 2 * c + 1];
#pragma unroll
            for (int r = 0; r < 4; ++r) {
                float xe = (kk == 0) ? xv[r].x : (kk == 1) ? xv[r].y : (kk == 2) ? xv[r].z : xv[r].w;
                acc[r][0] = fmaf(xe, w0, acc[r][0]);
                acc[r][1] = fmaf(xe, w1, acc[r][1]);
            }
        }
    }

#pragma unroll
    for (int r = 0; r < 4; ++r) {
        int n = n0 + s * 4 + r;
        if (n < NN) {
            float dn = dinv[n];
            out_f8[(size_t)n * 32 + c] = f2fp8x2(acc[r][0] * dn, acc[r][1] * dn);
        }
    }
}

// ---------------- aggregate: 8 nodes/wave, 2 batches x 4 simultaneous streams ----------------
__global__ __launch_bounds__(256) void k_aggregate(const unsigned int* __restrict__ hW8,  // fp8 rows: 16 uints
                                                   const int* __restrict__ srcs,
                                                   const int* __restrict__ row_ptr,
                                                   const float* __restrict__ dinv,
                                                   const float* __restrict__ bias,
                                                   unsigned int* __restrict__ outb) {    // bf16 rows: 32 uints
    int tid = threadIdx.x;
    int lane = tid & 63;
    int grp = lane >> 4;   // 0..3
    int li = lane & 15;
    int w = tid >> 6;
    int base = (blockIdx.x * 4 + w) * 8;   // NN = 12500*8, always valid

    // coalesced bounds load: lane i<=8 holds row_ptr[base+i]
    int rp = row_ptr[base + (lane <= 8 ? lane : 8)];
    float4 bv = ((const float4*)bias)[li];

#pragma unroll
    for (int q = 0; q < 2; ++q) {
        int n0 = base + 4 * q;
        int e0 = __shfl(rp, 4 * q + 0, 64);
        int f0 = __shfl(rp, 4 * q + 1, 64);
        int e1 = f0;
        int f1 = __shfl(rp, 4 * q + 2, 64);
        int e2 = f1;
        int f2 = __shfl(rp, 4 * q + 3, 64);
        int e3 = f2;
        int f3 = __shfl(rp, 4 * q + 4, 64);

        float A0 = 0.f, A1 = 0.f, A2 = 0.f, A3 = 0.f;
        float B0 = 0.f, B1 = 0.f, B2 = 0.f, B3 = 0.f;
        float C0 = 0.f, C1 = 0.f, C2 = 0.f, C3 = 0.f;
        float D0 = 0.f, D1 = 0.f, D2 = 0.f, D3 = 0.f;

        // self terms: one 256B coalesced gather covers all 4 nodes (grp g -> node n0+g)
        {
            unsigned int su = hW8[(size_t)(n0 + grp) * 16 + li];
            if (grp == 0)      fp8acc(su, A0, A1, A2, A3);
            else if (grp == 1) fp8acc(su, B0, B1, B2, B3);
            else if (grp == 2) fp8acc(su, C0, C1, C2, C3);
            else               fp8acc(su, D0, D1, D2, D3);
        }

        // quad main loop: 4 independent gathers in flight
        while (e0 + 3 < f0 && e1 + 3 < f1 && e2 + 3 < f2 && e3 + 3 < f3) {
            int s0 = srcs[e0 + grp];
            int s1 = srcs[e1 + grp];
            int s2 = srcs[e2 + grp];
            int s3 = srcs[e3 + grp];
            unsigned int u0 = hW8[(size_t)s0 * 16 + li];
            unsigned int u1 = hW8[(size_t)s1 * 16 + li];
            unsigned int u2 = hW8[(size_t)s2 * 16 + li];
            unsigned int u3 = hW8[(size_t)s3 * 16 + li];
            fp8acc(u0, A0, A1, A2, A3);
            fp8acc(u1, B0, B1, B2, B3);
            fp8acc(u2, C0, C1, C2, C3);
            fp8acc(u3, D0, D1, D2, D3);
            e0 += 4; e1 += 4; e2 += 4; e3 += 4;
        }
        // per-stream drains (wave-uniform bounds)
        while (e0 + 3 < f0) {
            int s0 = srcs[e0 + grp];
            unsigned int u0 = hW8[(size_t)s0 * 16 + li];
            fp8acc(u0, A0, A1, A2, A3);
            e0 += 4;
        }
        while (e1 + 3 < f1) {
            int s1 = srcs[e1 + grp];
            unsigned int u1 = hW8[(size_t)s1 * 16 + li];
            fp8acc(u1, B0, B1, B2, B3);
            e1 += 4;
        }
        while (e2 + 3 < f2) {
            int s2 = srcs[e2 + grp];
            unsigned int u2 = hW8[(size_t)s2 * 16 + li];
            fp8acc(u2, C0, C1, C2, C3);
            e2 += 4;
        }
        while (e3 + 3 < f3) {
            int s3 = srcs[e3 + grp];
            unsigned int u3 = hW8[(size_t)s3 * 16 + li];
            fp8acc(u3, D0, D1, D2, D3);
            e3 += 4;
        }
        // tails (0..3 edges each), predicated by group
        if (grp < f0 - e0) {
            int s0 = srcs[e0 + grp];
            unsigned int u0 = hW8[(size_t)s0 * 16 + li];
            fp8acc(u0, A0, A1, A2, A3);
        }
        if (grp < f1 - e1) {
            int s1 = srcs[e1 + grp];
            unsigned int u1 = hW8[(size_t)s1 * 16 + li];
            fp8acc(u1, B0, B1, B2, B3);
        }
        if (grp < f2 - e2) {
            int s2 = srcs[e2 + grp];
            unsigned int u2 = hW8[(size_t)s2 * 16 + li];
            fp8acc(u2, C0, C1, C2, C3);
        }
        if (grp < f3 - e3) {
            int s3 = srcs[e3 + grp];
            unsigned int u3 = hW8[(size_t)s3 * 16 + li];
            fp8acc(u3, D0, D1, D2, D3);
        }

        // cross-group reduce, all 4 streams
#define RED1(x) x += __shfl_xor(x, 16, 64)
#define RED2(x) x += __shfl_xor(x, 32, 64)
        RED1(A0); RED1(A1); RED1(A2); RED1(A3);
        RED1(B0); RED1(B1); RED1(B2); RED1(B3);
        RED1(C0); RED1(C1); RED1(C2); RED1(C3);
        RED1(D0); RED1(D1); RED1(D2); RED1(D3);
        RED2(A0); RED2(A1); RED2(A2); RED2(A3);
        RED2(B0); RED2(B1); RED2(B2); RED2(B3);
        RED2(C0); RED2(C1); RED2(C2); RED2(C3);
        RED2(D0); RED2(D1); RED2(D2); RED2(D3);
#undef RED1
#undef RED2

        // store: grp g stores node n0+g -> one fully coalesced 512B store
        {
            int n = n0 + grp;
            float s0v, s1v, s2v, s3v;
            if (grp == 0)      { s0v = A0; s1v = A1; s2v = A2; s3v = A3; }
            else if (grp == 1) { s0v = B0; s1v = B1; s2v = B2; s3v = B3; }
            else if (grp == 2) { s0v = C0; s1v = C1; s2v = C2; s3v = C3; }
            else               { s0v = D0; s1v = D1; s2v = D2; s3v = D3; }
            float dn = dinv[n];
            float v0 = fmaxf(fmaf(dn, s0v, bv.x), 0.0f);
            float v1 = fmaxf(fmaf(dn, s1v, bv.y), 0.0f);
            float v2 = fmaxf(fmaf(dn, s2v, bv.z), 0.0f);
            float v3 = fmaxf(fmaf(dn, s3v, bv.w), 0.0f);
            uint2 pk;
            pk.x = (unsigned int)f2bf(v0) | ((unsigned int)f2bf(v1) << 16);
            pk.y = (unsigned int)f2bf(v2) | ((unsigned int)f2bf(v3) << 16);
            ((uint2*)outb)[(size_t)n * 16 + li] = pk;
        }
    }
}

// ---------------- GEMM layers 2/3: bf16 in, fp8 out ----------------
__global__ __launch_bounds__(256) void k_gemm_bf(const unsigned short* __restrict__ X,
                                                 const float* __restrict__ W,
                                                 const float* __restrict__ dinv,
                                                 unsigned short* __restrict__ out_f8) {
    __shared__ float Wl[HID * HID];  // 16 KB
    __shared__ float xl[64 * HID];   // 16 KB
    int tid = threadIdx.x;
    int n0 = blockIdx.x * 64;

    {
        const float4* Wg = (const float4*)W;
        float4* Wl4 = (float4*)Wl;
#pragma unroll
        for (int i = 0; i < HID * HID / 4 / 256; ++i) Wl4[i * 256 + tid] = Wg[i * 256 + tid];
    }
    {
        const uint4* Xg = (const uint4*)X;
#pragma unroll
        for (int i = 0; i < 2; ++i) {
            int idx = i * 256 + tid;      // 0..511
            int ln = idx >> 3;            // local node
            int k0 = (idx & 7) * 8;
            int node = n0 + ln;
            float f[8];
            if (node < NN) {
                uint4 u = Xg[(size_t)n0 * 8 + idx];
                f[0] = bf2f((unsigned short)(u.x & 0xffff));
                f[1] = bf2f((unsigned short)(u.x >> 16));
                f[2] = bf2f((unsigned short)(u.y & 0xffff));
                f[3] = bf2f((unsigned short)(u.y >> 16));
                f[4] = bf2f((unsigned short)(u.z & 0xffff));
                f[5] = bf2f((unsigned short)(u.z >> 16));
                f[6] = bf2f((unsigned short)(u.w & 0xffff));
                f[7] = bf2f((unsigned short)(u.w >> 16));
            } else {
#pragma unroll
                for (int q = 0; q < 8; ++q) f[q] = 0.f;
            }
#pragma unroll
            for (int q = 0; q < 8; ++q) xl[ln * HID + k0 + q] = f[q];
        }
    }
    __syncthreads();

    int c = tid & 31;
    int s = tid >> 5;
    float acc[8][2];
#pragma unroll
    for (int r = 0; r < 8; ++r) { acc[r][0] = 0.f; acc[r][1] = 0.f; }

#pragma unroll 4
    for (int k0 = 0; k0 < HID; k0 += 4) {
        float4 xv[8];
#pragma unroll
        for (int r = 0; r < 8; ++r) xv[r] = *(const float4*)&xl[(s * 8 + r) * HID + k0];
#pragma unroll
        for (int kk = 0; kk < 4; ++kk) {
            float w0 = Wl[(k0 + kk) * HID + 2 * c];
            float w1 = Wl[(k0 + kk) * HID + 2 * c + 1];
#pragma unroll
            for (int r = 0; r < 8; ++r) {
                float xe = (kk == 0) ? xv[r].x : (kk == 1) ? xv[r].y : (kk == 2) ? xv[r].z : xv[r].w;
                acc[r][0] = fmaf(xe, w0, acc[r][0]);
                acc[r][1] = fmaf(xe, w1, acc[r][1]);
            }
        }
    }

#pragma unroll
    for (int r = 0; r < 8; ++r) {
        int n = n0 + s * 8 + r;
        if (n < NN) {
            float dn = dinv[n];
            out_f8[(size_t)n * 32 + c] = f2fp8x2(acc[r][0] * dn, acc[r][1] * dn);
        }
    }
}

// ---------------- pooling stage A: parallel partial sums over 128-node chunks ----------------
__global__ __launch_bounds__(256) void k_pool_partial(const unsigned short* __restrict__ h,
                                                      const int* __restrict__ batch,
                                                      float* __restrict__ sums) {
    int tid = threadIdx.x;
    int j = tid & 63;
    int w = tid >> 6;
    int chunk = blockIdx.x * 4 + w;
    int n0 = chunk * 128;
    if (n0 >= NN) return;
    int n1 = n0 + 128;
    if (n1 > NN) n1 = NN;
    float acc = 0.0f;
    int cur = batch[n0];
    for (int n = n0; n < n1; ++n) {
        int g = batch[n];
        if (g != cur) {
            atomicAdd(&sums[cur * HID + j], acc);
            acc = 0.0f;
            cur = g;
        }
        acc += bf2f(h[n * HID + j]);
    }
    atomicAdd(&sums[cur * HID + j], acc);
}

// ---------------- pooling stage B: mean + head ----------------
__global__ __launch_bounds__(64) void k_head(const float* __restrict__ sums, const int* __restrict__ start,
                                             const float* __restrict__ Wc, const float* __restrict__ bc,
                                             float* __restrict__ out) {
    int g = blockIdx.x;
    int j = threadIdx.x;
    float cnt = (float)(start[g + 1] - start[g]);
    float p = sums[g * HID + j] / fmaxf(cnt, 1.0f);
#pragma unroll
    for (int c = 0; c < NC; ++c) {
        float v = p * Wc[j * NC + c];
        for (int off = 32; off > 0; off >>= 1) v += __shfl_down(v, off);
        if (j == 0) out[g * NC + c] = v + bc[c];
    }
}

// ---------------- driver ----------------
extern "C" void kernel_launch(void* const* d_in, const int* in_sizes, int n_in,
                              void* d_out, int out_size, void* d_ws, size_t ws_size,
                              hipStream_t stream) {
    const float* x  = (const float*)d_in[0];
    const int* ei   = (const int*)d_in[1];
    const int* bat  = (const int*)d_in[2];
    const float* W1 = (const float*)d_in[3];
    const float* b1 = (const float*)d_in[4];
    const float* W2 = (const float*)d_in[5];
    const float* b2 = (const float*)d_in[6];
    const float* W3 = (const float*)d_in[7];
    const float* b3 = (const float*)d_in[8];
    const float* Wc = (const float*)d_in[9];
    const float* bc = (const float*)d_in[10];
    float* out = (float*)d_out;

    const int* src = ei;
    const int* dst = ei + NE;

    // workspace layout (bytes), all 16B-aligned
    char* wsb = (char*)d_ws;
    float* dinv         = (float*)wsb;                          // NN f32
    int*   row_ptr      = (int*)(wsb + 400000);                 // NN+1
    int*   srcs         = (int*)(wsb + 800016);                 // NE
    unsigned short* hF8 = (unsigned short*)(wsb + 5600016);     // NN*HID fp8 (6.4 MB)
    unsigned short* hBF = (unsigned short*)(wsb + 18400016);    // NN*HID bf16 (12.8 MB)
    int*   cnt          = (int*)(wsb + 31200016);               // NN
    int*   exc          = (int*)(wsb + 31600016);               // NN
    int*   bsum         = (int*)(wsb + 32000016);               // 512
    int*   rank         = (int*)(wsb + 32002064);               // NE
    int*   start        = (int*)(wsb + 36802064);               // NG+1
    float* sums         = (float*)(wsb + 36803088);             // NG*HID f32 (32 KB)

    const int gE = (NE + 255) / 256;  // 4688

    // CSR build + normalization
    hipMemsetAsync(cnt, 0, NN * sizeof(int), stream);
    hipMemsetAsync(sums, 0, NG * HID * sizeof(float), stream);
    k_hist<<<gE, 256, 0, stream>>>(dst, cnt, rank);
    k_scan1<<<NB, 256, 0, stream>>>(cnt, exc, bsum, dinv);
    k_scan23<<<NB, 256, 0, stream>>>(exc, bsum, row_ptr);

    // bucket scatter + layer-1 GEMM (fp8 out) + pool bounds, one grid
    k_fused1<<<GB + G1 + NB, 256, 0, stream>>>(x, W1, dinv, hF8, src, dst, row_ptr, rank, srcs, bat, start);

    // layers: gemm writes fp8 (gathered), aggregate writes bf16 (streamed)
    k_aggregate<<<NN / 32, 256, 0, stream>>>((const unsigned int*)hF8, srcs, row_ptr, dinv, b1, (unsigned int*)hBF);
    k_gemm_bf<<<(NN + 63) / 64, 256, 0, stream>>>(hBF, W2, dinv, hF8);
    k_aggregate<<<NN / 32, 256, 0, stream>>>((const unsigned int*)hF8, srcs, row_ptr, dinv, b2, (unsigned int*)hBF);
    k_gemm_bf<<<(NN + 63) / 64, 256, 0, stream>>>(hBF, W3, dinv, hF8);
    k_aggregate<<<NN / 32, 256, 0, stream>>>((const unsigned int*)hF8, srcs, row_ptr, dinv, b3, (unsigned int*)hBF);

    // pooling: parallel partials + tiny head
    k_pool_partial<<<196, 256, 0, stream>>>(hBF, bat, sums);
    k_head<<<NG, 64, 0, stream>>>(sums, start, Wc, bc, out);
}